// Round 2
// baseline (131.092 us; speedup 1.0000x reference)
//
#include <hip/hip_runtime.h>
#include <hip/hip_bf16.h>
#include <math.h>

#define NB   256
#define KIN  1024
#define ND   512
#define NP   2048
#define NTOT 4096   // Wm rows + proxy rows stacked

typedef __bf16 bf16x8 __attribute__((ext_vector_type(8)));
typedef float  f32x4  __attribute__((ext_vector_type(4)));
typedef unsigned short ush8 __attribute__((ext_vector_type(8)));

// ws byte offsets (16B aligned)
#define OFF_WPB    0u          // 4096*512 bf16 = 4 MB   (proxy rows pre-scaled by 2)
#define OFF_FEAT32 4194304u    // 256*512 f32   = 512 KB (feat + bias, for row norms)
#define OFF_FEATB  4718592u    // 256*512 bf16  = 256 KB (feat + bias, head A operand)
#define OFF_PN2    4980736u    // 2048 f32      = 8 KB
#define OFF_LOGITS 4988928u    // 256*2048 f32  = 2 MB

__device__ __forceinline__ ush8 pack8(float4 f0, float4 f1) {
    union { ush8 v; __hip_bfloat162 h[4]; } o;
    o.h[0] = __float22bfloat162_rn(make_float2(f0.x, f0.y));
    o.h[1] = __float22bfloat162_rn(make_float2(f0.z, f0.w));
    o.h[2] = __float22bfloat162_rn(make_float2(f1.x, f1.y));
    o.h[3] = __float22bfloat162_rn(make_float2(f1.z, f1.w));
    return o.v;
}
__device__ __forceinline__ unsigned short f2bf(float v) {
    union { __hip_bfloat16 h; unsigned short u; } c;
    c.h = __float2bfloat16(v);
    return c.u;
}
// load 8 consecutive fp32, convert to bf16x8 fragment (register-only)
__device__ __forceinline__ bf16x8 ldf8(const float* p) {
    float4 v0 = *(const float4*)p, v1 = *(const float4*)(p + 4);
    union { ush8 u; bf16x8 b; } c;
    c.u = pack8(v0, v1);
    return c.b;
}
// load 8 consecutive bf16 as fragment
__device__ __forceinline__ bf16x8 ldb8(const unsigned short* p) {
    union { ush8 u; bf16x8 b; } c;
    c.u = *(const ush8*)p;
    return c.b;
}

// ---------------------------------------------------------------------------
// K_A: block-specialized fused kernel. NO LDS, NO barriers.
//  blocks 0..31   : feat GEMM, register-direct fragments. Each of the 4 waves
//                   owns one independent 32x32 output tile, full K=1024.
//                   128 tiles total (8 m-tiles x 16 n-tiles).
//  blocks 32..287 : cast Wm (x1) / prox (x2) -> WPb, pn2 = ||prox||^2,
//                   block 32 zeroes the tail accumulators.
// ---------------------------------------------------------------------------
__global__ __launch_bounds__(256) void k_fa(
    const float* __restrict__ x, const float* __restrict__ Wb,
    const float* __restrict__ bb,
    const float* __restrict__ Wm, const float* __restrict__ prox,
    unsigned short* __restrict__ WPb, float* __restrict__ pn2,
    float* __restrict__ feat32, unsigned short* __restrict__ featb,
    float* __restrict__ tail)
{
    const int t = threadIdx.x, lane = t & 63, w = t >> 6;

    if (blockIdx.x >= 32) {
        // ---------------- prep: cast 16 rows per block ----------------
        const int pb = blockIdx.x - 32;            // 0..255
        if (pb == 0 && t < 2) tail[t] = 0.f;       // zero loss accumulators
#pragma unroll
        for (int i = 0; i < 4; ++i) {
            const int r = pb * 16 + w * 4 + i;     // 0..4095
            const float* src = (r < NP) ? (Wm + (size_t)r * ND)
                                        : (prox + (size_t)(r - NP) * ND);
            float4 v0 = *(const float4*)(src + lane * 8);
            float4 v1 = *(const float4*)(src + lane * 8 + 4);
            if (r < NP) {
                *(ush8*)(WPb + (size_t)r * ND + lane * 8) = pack8(v0, v1);
            } else {
                float s = v0.x*v0.x + v0.y*v0.y + v0.z*v0.z + v0.w*v0.w
                        + v1.x*v1.x + v1.y*v1.y + v1.z*v1.z + v1.w*v1.w;
#pragma unroll
                for (int off = 32; off; off >>= 1) s += __shfl_down(s, off);
                if (lane == 0) pn2[r - NP] = s;
                // store 2*prox so head epilogue is uniformly v +/- cadd.
                // bf16(2v) == 2*bf16(v) exactly (exponent shift).
                float4 d0 = make_float4(v0.x + v0.x, v0.y + v0.y,
                                        v0.z + v0.z, v0.w + v0.w);
                float4 d1 = make_float4(v1.x + v1.x, v1.y + v1.y,
                                        v1.z + v1.z, v1.w + v1.w);
                *(ush8*)(WPb + (size_t)r * ND + lane * 8) = pack8(d0, d1);
            }
        }
        return;
    }

    // ------------- feat GEMM: one 32x32 tile per wave, reg-direct -------------
    const int wid = blockIdx.x * 4 + w;            // 0..127
    const int m0 = (wid >> 4) * 32, n0 = (wid & 15) * 32;
    const int fr = lane & 15, ck = (lane >> 4) * 8;
    const float* pA0 = x  + (size_t)(m0 + fr) * KIN + ck;
    const float* pA1 = pA0 + 16 * KIN;
    const float* pB0 = Wb + (size_t)(n0 + fr) * KIN + ck;
    const float* pB1 = pB0 + 16 * KIN;
    f32x4 acc[2][2] = {};
#pragma unroll 4
    for (int ks = 0; ks < KIN / 32; ++ks) {
        const int off = ks * 32;
        bf16x8 af0 = ldf8(pA0 + off);
        bf16x8 af1 = ldf8(pA1 + off);
        bf16x8 bf0 = ldf8(pB0 + off);
        bf16x8 bf1 = ldf8(pB1 + off);
        acc[0][0] = __builtin_amdgcn_mfma_f32_16x16x32_bf16(af0, bf0, acc[0][0], 0, 0, 0);
        acc[0][1] = __builtin_amdgcn_mfma_f32_16x16x32_bf16(af0, bf1, acc[0][1], 0, 0, 0);
        acc[1][0] = __builtin_amdgcn_mfma_f32_16x16x32_bf16(af1, bf0, acc[1][0], 0, 0, 0);
        acc[1][1] = __builtin_amdgcn_mfma_f32_16x16x32_bf16(af1, bf1, acc[1][1], 0, 0, 0);
    }

    const int q = lane >> 4;
#pragma unroll
    for (int i = 0; i < 2; ++i)
#pragma unroll
        for (int j = 0; j < 2; ++j) {
            const int n = n0 + 16 * j + fr;
            const float bbn = bb[n];
#pragma unroll
            for (int r = 0; r < 4; ++r) {
                const int m = m0 + 16 * i + q * 4 + r;
                const float v = acc[i][j][r] + bbn;
                feat32[m * ND + n] = v;
                featb [m * ND + n] = f2bf(v);
            }
        }
}

// ---------------------------------------------------------------------------
// K_B: head GEMM, register-direct, NO LDS/barriers. Each wave owns one
// independent 32x64 output tile (8 m-tiles x 64 n-tiles = 512 waves =
// 128 blocks). n<2048: out = v + bm ; n>=2048: logits = v - pn2
// (WPb proxy rows pre-scaled by 2).
// ---------------------------------------------------------------------------
__global__ __launch_bounds__(256) void k_fb(
    const unsigned short* __restrict__ featb,
    const unsigned short* __restrict__ WPb,
    const float* __restrict__ bm, const float* __restrict__ pn2,
    float* __restrict__ out, float* __restrict__ logits)
{
    const int t = threadIdx.x, lane = t & 63, w = t >> 6;
    const int wid = blockIdx.x * 4 + w;            // 0..511
    const int m0 = (wid >> 6) * 32, n0 = (wid & 63) * 64;
    const int fr = lane & 15, ck = (lane >> 4) * 8;

    const unsigned short* pA0 = featb + (size_t)(m0 + fr) * ND + ck;
    const unsigned short* pA1 = pA0 + 16 * ND;
    const unsigned short* pB0 = WPb + (size_t)(n0      + fr) * ND + ck;
    const unsigned short* pB1 = WPb + (size_t)(n0 + 16 + fr) * ND + ck;
    const unsigned short* pB2 = WPb + (size_t)(n0 + 32 + fr) * ND + ck;
    const unsigned short* pB3 = WPb + (size_t)(n0 + 48 + fr) * ND + ck;

    f32x4 acc[2][4] = {};
#pragma unroll 4
    for (int ks = 0; ks < ND / 32; ++ks) {
        const int off = ks * 32;
        bf16x8 af0 = ldb8(pA0 + off);
        bf16x8 af1 = ldb8(pA1 + off);
        bf16x8 bf0 = ldb8(pB0 + off);
        bf16x8 bf1 = ldb8(pB1 + off);
        bf16x8 bf2 = ldb8(pB2 + off);
        bf16x8 bf3 = ldb8(pB3 + off);
        acc[0][0] = __builtin_amdgcn_mfma_f32_16x16x32_bf16(af0, bf0, acc[0][0], 0, 0, 0);
        acc[0][1] = __builtin_amdgcn_mfma_f32_16x16x32_bf16(af0, bf1, acc[0][1], 0, 0, 0);
        acc[0][2] = __builtin_amdgcn_mfma_f32_16x16x32_bf16(af0, bf2, acc[0][2], 0, 0, 0);
        acc[0][3] = __builtin_amdgcn_mfma_f32_16x16x32_bf16(af0, bf3, acc[0][3], 0, 0, 0);
        acc[1][0] = __builtin_amdgcn_mfma_f32_16x16x32_bf16(af1, bf0, acc[1][0], 0, 0, 0);
        acc[1][1] = __builtin_amdgcn_mfma_f32_16x16x32_bf16(af1, bf1, acc[1][1], 0, 0, 0);
        acc[1][2] = __builtin_amdgcn_mfma_f32_16x16x32_bf16(af1, bf2, acc[1][2], 0, 0, 0);
        acc[1][3] = __builtin_amdgcn_mfma_f32_16x16x32_bf16(af1, bf3, acc[1][3], 0, 0, 0);
    }

    const bool isProxy = (n0 >= NP);               // tile-uniform (64 | 2048)
    const int q = lane >> 4;
#pragma unroll
    for (int j = 0; j < 4; ++j) {
        const int n = n0 + 16 * j + fr;
        const float cadd = isProxy ? pn2[n - NP] : bm[n];
#pragma unroll
        for (int i = 0; i < 2; ++i)
#pragma unroll
            for (int r = 0; r < 4; ++r) {
                const int m = m0 + 16 * i + q * 4 + r;
                const float v = acc[i][j][r];
                if (isProxy) logits[m * NP + (n - NP)] = v - cadd;
                else         out[m * NP + n] = v + cadd;
            }
    }
}

__device__ __forceinline__ float block_reduce(float v, float* sred, int op)
{
    const int lane = threadIdx.x & 63, wave = threadIdx.x >> 6;
#pragma unroll
    for (int off = 32; off; off >>= 1) {
        float o = __shfl_down(v, off);
        v = op ? fmaxf(v, o) : (v + o);
    }
    if (lane == 0) sred[wave] = v;
    __syncthreads();
    if (threadIdx.x == 0) {
        float r = sred[0];
#pragma unroll
        for (int wv = 1; wv < 4; ++wv) r = op ? fmaxf(r, sred[wv]) : (r + sred[wv]);
        sred[0] = r;
    }
    __syncthreads();
    float r = sred[0];
    __syncthreads();
    return r;
}

// K_C: per-row logsumexp + gather + feat row norm, accumulated straight into
// the two output tail scalars.
__global__ __launch_bounds__(256) void k_fc(
    const float* __restrict__ feat32, const float* __restrict__ logits,
    const int* __restrict__ y, float* __restrict__ tail)
{
    __shared__ float sred[4];
    const int b = blockIdx.x, t = threadIdx.x;

    float v0 = feat32[b * ND + t];           // bias already folded in
    float v1 = feat32[b * ND + t + 256];
    float fn2 = block_reduce(v0 * v0 + v1 * v1, sred, 0);

    const float* lr = logits + (size_t)b * NP;
    float lv[8], mx = -INFINITY;
#pragma unroll
    for (int j = 0; j < 8; ++j) { lv[j] = lr[t + 256 * j]; mx = fmaxf(mx, lv[j]); }
    float MX = block_reduce(mx, sred, 1);
    float es = 0.f;
#pragma unroll
    for (int j = 0; j < 8; ++j) es += __expf(lv[j] - MX);
    float SUM = block_reduce(es, sred, 0);

    if (t == 0) {
        float ly = lr[y[b]];
        float lp = ly - MX - __logf(SUM);
        atomicAdd(&tail[0], -lp * (1.0f / (float)NB));
        atomicAdd(&tail[1], sqrtf(fn2) * (1.0f / (float)NB));
    }
}

extern "C" void kernel_launch(void* const* d_in, const int* in_sizes, int n_in,
                              void* d_out, int out_size, void* d_ws, size_t ws_size,
                              hipStream_t stream)
{
    const float* x       = (const float*)d_in[0];
    const int*   y       = (const int*)  d_in[1];
    const float* Wb      = (const float*)d_in[2];
    const float* bb      = (const float*)d_in[3];
    const float* Wm      = (const float*)d_in[4];
    const float* bm      = (const float*)d_in[5];
    const float* proxies = (const float*)d_in[6];

    char* ws = (char*)d_ws;
    unsigned short* WPb    = (unsigned short*)(ws + OFF_WPB);
    float*          feat32 = (float*)(ws + OFF_FEAT32);
    unsigned short* featb  = (unsigned short*)(ws + OFF_FEATB);
    float*          pn2    = (float*)(ws + OFF_PN2);
    float*          logits = (float*)(ws + OFF_LOGITS);

    float* out  = (float*)d_out;
    float* tail = out + (size_t)NB * NP;

    k_fa<<<dim3(288), dim3(256), 0, stream>>>(
        x, Wb, bb, Wm, proxies, WPb, pn2, feat32, featb, tail);
    k_fb<<<dim3(128), dim3(256), 0, stream>>>(
        featb, WPb, bm, pn2, out, logits);
    k_fc<<<dim3(NB), dim3(256), 0, stream>>>(feat32, logits, y, tail);
}